// Round 3
// baseline (179.936 us; speedup 1.0000x reference)
//
#include <hip/hip_runtime.h>

// Until operator: r[t] = max( min(1,psi[t]), min(phi[t], r[t+1]) ), r[T] = -inf.
// f(x)=max(a,min(b,x)) closed under composition (f earlier in time):
//   (f o g): A = max(a_f, min(b_f, a_g)), B = min(b_f, b_g)
// float4 = 2 timesteps x 2 channels = one "pair entry". Row = 4096 entries.
//
// R7 structural change vs R6: block = 1024 threads (16 waves), each wave owns
// a 256-entry segment (ONE round; 4 entries/lane) instead of 512 (two rounds).
// Same ~66KB LDS per block, but per-thread LDS halves -> 2 blocks/CU is now
// 2048 threads/CU = 100% static occupancy (was 50%). The phase-synchronized
// load->quiet->store burst pattern (why HBM sat at 2 TB/s with every pipe
// idle) now has 2x the out-of-phase waves to smooth it. To keep total regs
// <=64 (8 waves/SIMD, no hidden AGPR parking), P/V are NOT held to emit:
// emit reloads phi/psi (R6 counters proved the reload is L2/L3-served, an
// issue-slot cost only -- occupancy now hides it). Peak live ~48 regs, so
// launch_bounds(1024,8)'s 64-cap has headroom (R5 spill trap: live 92 vs
// cap 64; not the case here). Still ONE real barrier (ssum).

#define T_LEN 8192
#define NW    16            // waves per block = segments per row
#define BLOCK (NW * 64)     // 1024

__device__ __forceinline__ float rfl(float x) {
    return __int_as_float(__builtin_amdgcn_readfirstlane(__float_as_int(x)));
}

// Wave-level ordering fence for wave-private LDS reuse: prevents the compiler
// from moving LDS accesses across it; HW executes a wave's DS ops in order.
__device__ __forceinline__ void wave_lds_fence() {
    __asm__ volatile("" ::: "memory");
    __builtin_amdgcn_wave_barrier();
    __asm__ volatile("" ::: "memory");
}

__global__ __launch_bounds__(BLOCK, 8) void until_kernel(
    const float* __restrict__ phi, const float* __restrict__ psi,
    float* __restrict__ out)
{
    const int  row  = blockIdx.x;
    const int  tid  = threadIdx.x;
    const int  w    = tid >> 6;
    const int  lane = tid & 63;
    const float NEG = -__builtin_huge_valf();
    const float POS =  __builtin_huge_valf();

    const size_t segf4 = (size_t)row * (T_LEN / 2) + (size_t)w * 256;
    const float4* __restrict__ phi4 = (const float4*)phi + segf4;
    const float4* __restrict__ psi4 = (const float4*)psi + segf4;
    float4* __restrict__ out4 = (float4*)out + segf4;

    // Per-wave private 1024-float region:
    //   G phase:  4 SoA comps x 256 entries (GAx/GAy/GBx/GBy)
    //   carry phase (reuses GAx/GAy area): CX[e] at wl[e], CY[e] at wl[256+e]
    __shared__ alignas(16) float lds[NW * 1024];
    __shared__ float4 ssum[NW];
    float* wl = lds + w * 1024;

    // ---- burst: 8 global loads back-to-back ----
    {
        float4 P[4], Q[4];
#pragma unroll
        for (int k = 0; k < 4; ++k) {
            P[k] = phi4[k * 64 + lane];
            Q[k] = psi4[k * 64 + lane];
        }

        // ---- build pair functions G, SoA write (dense, conflict-free) ----
#pragma unroll
        for (int k = 0; k < 4; ++k) {
            float* base = wl + k * 64 + lane;
            float v0x = fminf(1.f, Q[k].x), v0y = fminf(1.f, Q[k].y);
            float v1x = fminf(1.f, Q[k].z), v1y = fminf(1.f, Q[k].w);
            base[0]   = fmaxf(v0x, fminf(P[k].x, v1x));  // GAx
            base[256] = fmaxf(v0y, fminf(P[k].y, v1y));  // GAy
            base[512] = fminf(P[k].x, P[k].z);           // GBx
            base[768] = fminf(P[k].y, P[k].w);           // GBy
        }
    }
    wave_lds_fence();   // wave-private transpose: no block barrier needed

    // ---- transposed read (b128, dense) + compose + suffix scan ----
    float4 GAx, GAy, GBx, GBy;
    GAx = *(const float4*)(wl + 0 * 256 + lane * 4);
    GAy = *(const float4*)(wl + 1 * 256 + lane * 4);
    GBx = *(const float4*)(wl + 2 * 256 + lane * 4);
    GBy = *(const float4*)(wl + 3 * 256 + lane * 4);

    // local compose right-to-left: H = G_e0 o G_e1 o G_e2 o G_e3
    float hax = GAx.w, hay = GAy.w, hbx = GBx.w, hby = GBy.w;
    hax = fmaxf(GAx.z, fminf(GBx.z, hax));
    hay = fmaxf(GAy.z, fminf(GBy.z, hay));
    hbx = fminf(GBx.z, hbx);
    hby = fminf(GBy.z, hby);
    hax = fmaxf(GAx.y, fminf(GBx.y, hax));
    hay = fmaxf(GAy.y, fminf(GBy.y, hay));
    hbx = fminf(GBx.y, hbx);
    hby = fminf(GBy.y, hby);
    hax = fmaxf(GAx.x, fminf(GBx.x, hax));
    hay = fmaxf(GAy.x, fminf(GBy.x, hay));
    hbx = fminf(GBx.x, hbx);
    hby = fminf(GBy.x, hby);

    // 64-lane inclusive SUFFIX scan (toward lane 63)
#pragma unroll
    for (int off = 1; off < 64; off <<= 1) {
        float gax = __shfl_down(hax, off), gay = __shfl_down(hay, off);
        float gbx = __shfl_down(hbx, off), gby = __shfl_down(hby, off);
        bool  val = (lane + off) < 64;
        gax = val ? gax : NEG;  gay = val ? gay : NEG;
        gbx = val ? gbx : POS;  gby = val ? gby : POS;
        hax = fmaxf(hax, fminf(hbx, gax));
        hay = fmaxf(hay, fminf(hby, gay));
        hbx = fminf(hbx, gbx);
        hby = fminf(hby, gby);
    }
    const float Sax = hax, Say = hay, Sbx = hbx, Sby = hby;

    // ---- segment summary = S[lane 0] -> ssum (the ONE real barrier) ----
    if (lane == 0) ssum[w] = make_float4(Sax, Say, Sbx, Sby);
    __syncthreads();
    float rcx = NEG, rcy = NEG;   // carry entering this segment's right edge
    for (int j = NW - 1; j > w; --j) {
        float4 s = ssum[j];
        rcx = fmaxf(s.x, fminf(s.z, rcx));
        rcy = fmaxf(s.y, fminf(s.w, rcy));
    }

    // ---- per-entry carries -> wave-private LDS (b128, dense) ----
    // y = value at lane's LEFT edge = S[lane](r_in)
    {
        float yx = fmaxf(Sax, fminf(Sbx, rcx));
        float yy = fmaxf(Say, fminf(Sby, rcy));
        // carry entering lane's rightmost entry = y_{lane+1} (lane63: r_in)
        float cx = __shfl_down(yx, 1), cy = __shfl_down(yy, 1);
        if (lane == 63) { cx = rcx; cy = rcy; }
        float4 CX, CY;
        CX.w = cx;
        CY.w = cy;
        CX.z = fmaxf(GAx.w, fminf(GBx.w, CX.w));
        CY.z = fmaxf(GAy.w, fminf(GBy.w, CY.w));
        CX.y = fmaxf(GAx.z, fminf(GBx.z, CX.z));
        CY.y = fmaxf(GAy.z, fminf(GBy.z, CY.z));
        CX.x = fmaxf(GAx.y, fminf(GBx.y, CX.y));
        CY.x = fmaxf(GAy.y, fminf(GBy.y, CY.y));
        *(float4*)(wl +       lane * 4) = CX;  // CX[e] at wl[e]
        *(float4*)(wl + 256 + lane * 4) = CY;  // CY[e] at wl[256+e]
    }
    wave_lds_fence();   // wave-private carry handoff: no block barrier

    // ---- emit outputs: coalesced reload (L2/L3-warm) + carry from LDS ----
#pragma unroll
    for (int k = 0; k < 4; ++k) {
        const int e = k * 64 + lane;
        float4 P2 = phi4[e];
        float4 Q2 = psi4[e];
        float cx = wl[e];          // r at this entry's right edge
        float cy = wl[256 + e];
        float r1x = fmaxf(fminf(1.f, Q2.z), fminf(P2.z, cx));
        float r1y = fmaxf(fminf(1.f, Q2.w), fminf(P2.w, cy));
        float r0x = fmaxf(fminf(1.f, Q2.x), fminf(P2.x, r1x));
        float r0y = fmaxf(fminf(1.f, Q2.y), fminf(P2.y, r1y));
        out4[e] = make_float4(r0x, r0y, r1x, r1y);
    }
}

extern "C" void kernel_launch(void* const* d_in, const int* in_sizes, int n_in,
                              void* d_out, int out_size, void* d_ws, size_t ws_size,
                              hipStream_t stream) {
    const float* phi = (const float*)d_in[0];
    const float* psi = (const float*)d_in[1];
    float* out = (float*)d_out;
    const int Bn = in_sizes[0] / (T_LEN * 2);  // = 1024
    until_kernel<<<Bn, BLOCK, 0, stream>>>(phi, psi, out);
}